// Round 6
// baseline (703.731 us; speedup 1.0000x reference)
//
#include <hip/hip_runtime.h>
#include <hip/hip_cooperative_groups.h>
#include <cmath>

namespace cg = cooperative_groups;

// ---------------------------------------------------------------------------
// min_max_net: w' = weight with montn columns squared; y = x @ w'^T + bias;
// out[b] = (rand_u[b] < sigmoid(max_g min_{j in g} y[b, g*64+j])) ? 1 : 0
//
// R15: single persistent COOPERATIVE kernel (512 blocks = 2/CU co-resident)
// with 5 phases separated by grid.sync() -- eliminates 4 kernel-boundary
// overheads (the unaccounted ~80-100us of R14's non-gemm time) and replaces
// gemm's contended per-row atomicMax (R14: +4.5us, 4MB write) with plain
// writes to a [8192][16] pmax buffer (LDS-combined across wn waves).
// GEMM body frozen at R9's verified 128x256 structure (each block: 2 tiles).
// Fallback (small ws or coop-launch rejected): R14 multi-kernel chain.
// ---------------------------------------------------------------------------

typedef _Float16 f16x8 __attribute__((ext_vector_type(8)));
typedef float f32x4 __attribute__((ext_vector_type(4)));

#define MARGIN_EPS 4e-3f
#define MAX_UNDEC 96

__device__ __forceinline__ void async_load16(const void* gptr, void* lptr) {
  __builtin_amdgcn_global_load_lds(
      (const __attribute__((address_space(1))) void*)gptr,
      (__attribute__((address_space(3))) void*)lptr, 16, 0, 0);
}

__device__ __forceinline__ float us2f(unsigned short u) {
  return (float)__builtin_bit_cast(_Float16, u);
}

// order-preserving float -> uint key (fallback path only)
__device__ __forceinline__ unsigned f2key(float f) {
  unsigned b = __float_as_uint(f);
  return (b & 0x80000000u) ? ~b : (b | 0x80000000u);
}
__device__ __forceinline__ float key2f(unsigned e) {
  unsigned b = (e & 0x80000000u) ? (e ^ 0x80000000u) : ~e;
  return __uint_as_float(b);
}

// ===========================================================================
// R15 fused cooperative kernel
// ===========================================================================
__global__ __launch_bounds__(256, 2) void fused_all(
    const float* __restrict__ x, const float* __restrict__ wgt,
    const float* __restrict__ bias, const float* __restrict__ rand_u,
    const int* __restrict__ montn, float* __restrict__ out,
    unsigned short* __restrict__ xo, unsigned short* __restrict__ wo,
    int* __restrict__ count, int* __restrict__ undec,
    float* __restrict__ ybuf, float* __restrict__ pmax) {
  __shared__ __align__(16) char smem_raw[49152];
  cg::grid_group grid = cg::this_grid();
  const int b = blockIdx.x;
  const int t = threadIdx.x;
  const int lane = t & 63, w = t >> 6;

  // ---------------- phase 1: convert (24 rows/block), count=0 --------------
  {
    unsigned* msk = (unsigned*)smem_raw;
    if (b == 0 && t == 0) *count = 0;
    if (t < 64) msk[t] = 0u;
    __syncthreads();
    for (int j = t; j < 512; j += 256) {
      const int c = montn[j];
      atomicOr(&msk[c >> 5], 1u << (c & 31));
    }
    __syncthreads();
    const int l = lane;
#pragma unroll 1
    for (int i = 0; i < 6; ++i) {
      const int r = b * 24 + i * 4 + w;
      const int use_mask = (r >= 8192) ? 1 : 0;   // wave-uniform
      const float* rowp = use_mask ? (wgt + (size_t)(r - 8192) * 2048)
                                   : (x + (size_t)r * 2048);
      unsigned short* up = use_mask ? (wo + (size_t)(r - 8192) * 2048)
                                    : (xo + (size_t)r * 2048);
      float4 v[4][2];
#pragma unroll
      for (int p = 0; p < 4; ++p) {
        v[p][0] = ((const float4*)rowp)[p * 128 + 2 * l];
        v[p][1] = ((const float4*)rowp)[p * 128 + 2 * l + 1];
      }
      unsigned mw[4];
#pragma unroll
      for (int p = 0; p < 4; ++p)
        mw[p] = use_mask ? msk[p * 16 + (l >> 2)] : 0u;
#pragma unroll
      for (int p = 0; p < 4; ++p) {
        float f[8];
        f[0] = v[p][0].x; f[1] = v[p][0].y; f[2] = v[p][0].z; f[3] = v[p][0].w;
        f[4] = v[p][1].x; f[5] = v[p][1].y; f[6] = v[p][1].z; f[7] = v[p][1].w;
        unsigned short hs[8];
#pragma unroll
        for (int c = 0; c < 8; ++c) {
          float g = f[c];
          if ((mw[p] >> (8 * (l & 3) + c)) & 1u) g = g * g;
          hs[c] = __builtin_bit_cast(unsigned short, (_Float16)g);   // RTNE
        }
        uint4 H;
        H.x = (unsigned)hs[0] | ((unsigned)hs[1] << 16);
        H.y = (unsigned)hs[2] | ((unsigned)hs[3] << 16);
        H.z = (unsigned)hs[4] | ((unsigned)hs[5] << 16);
        H.w = (unsigned)hs[6] | ((unsigned)hs[7] << 16);
        *((uint4*)(up + p * 512 + 8 * l)) = H;
      }
    }
  }
  __threadfence();
  grid.sync();

  // ---------------- phase 2: GEMM (R9 body), 2 tiles/block ------------------
  {
    unsigned short* As = (unsigned short*)smem_raw;   // 128*64 = 16 KB
    unsigned short* Bs = As + 128 * 64;               // 256*64 = 32 KB
    const int wm = w >> 1, wn = w & 1;
    const int rowBase = w * 8 + (lane >> 3);
    const int gchunk = ((lane & 7) ^ ((lane >> 3) & 7)) * 8;  // ushort off
    const int am = lane & 15, quad = lane >> 4;
    int arow[4], brow[8], swz[2];
#pragma unroll
    for (int i = 0; i < 4; ++i) arow[i] = (wm * 64 + i * 16 + am) * 64;
#pragma unroll
    for (int j = 0; j < 8; ++j) brow[j] = (wn * 128 + j * 16 + am) * 64;
#pragma unroll
    for (int h = 0; h < 2; ++h) swz[h] = (((h << 2) + quad) ^ (am & 7)) * 8;
    unsigned short* ldsA0 = As + w * 512;
    unsigned short* ldsB0 = Bs + w * 512;

#pragma unroll 1
    for (int tt = 0; tt < 2; ++tt) {
      const int lin = b + tt * 512;
      const int sid = lin >> 3;
      const int m0 = (sid >> 1) * 128;
      const int nb = (lin & 7) * 2 + (sid & 1);
      const int n0 = nb * 256;
      const size_t gA0 = (size_t)(m0 + rowBase) * 2048 + gchunk;
      const size_t gB0 = (size_t)(n0 + rowBase) * 2048 + gchunk;

      f32x4 acc[4][8];
#pragma unroll
      for (int i = 0; i < 4; ++i)
#pragma unroll
        for (int j = 0; j < 8; ++j) acc[i][j] = (f32x4){0.f, 0.f, 0.f, 0.f};

#pragma unroll 1
      for (int it = 0; it < 32; ++it) {
        const int kin = it * 64;
        __syncthreads();  // prev iteration's LDS reads / pbuf reuse complete
#pragma unroll
        for (int c = 0; c < 4; ++c)
          async_load16(xo + gA0 + (size_t)(c * 32) * 2048 + kin,
                       ldsA0 + c * 2048);
#pragma unroll
        for (int c = 0; c < 8; ++c)
          async_load16(wo + gB0 + (size_t)(c * 32) * 2048 + kin,
                       ldsB0 + c * 2048);
        __syncthreads();  // staging complete (drains vmcnt)
#pragma unroll
        for (int h = 0; h < 2; ++h) {
          f16x8 av[4], bv[8];
#pragma unroll
          for (int i = 0; i < 4; ++i)
            av[i] = *(const f16x8*)(As + arow[i] + swz[h]);
#pragma unroll
          for (int j = 0; j < 8; ++j)
            bv[j] = *(const f16x8*)(Bs + brow[j] + swz[h]);
#pragma unroll
          for (int mb = 0; mb < 4; ++mb)
#pragma unroll
            for (int nb8 = 0; nb8 < 8; ++nb8)
              acc[mb][nb8] = __builtin_amdgcn_mfma_f32_16x16x32_f16(
                  av[mb], bv[nb8], acc[mb][nb8], 0, 0, 0);
        }
      }

      // epilogue: bias + per-group min; LDS-combine wn pair; plain store.
      float bv8[8];
#pragma unroll
      for (int nb8 = 0; nb8 < 8; ++nb8)
        bv8[nb8] = bias[n0 + wn * 128 + nb8 * 16 + am];
      float vml[4][4];
#pragma unroll
      for (int mb = 0; mb < 4; ++mb) {
#pragma unroll
        for (int reg = 0; reg < 4; ++reg) {
          float vm = -3.4e38f;
#pragma unroll
          for (int hh = 0; hh < 2; ++hh) {
            float v = fminf(
                fminf(acc[mb][4 * hh + 0][reg] + bv8[4 * hh + 0],
                      acc[mb][4 * hh + 1][reg] + bv8[4 * hh + 1]),
                fminf(acc[mb][4 * hh + 2][reg] + bv8[4 * hh + 2],
                      acc[mb][4 * hh + 3][reg] + bv8[4 * hh + 3]));
            v = fminf(v, __shfl_xor(v, 1, 64));
            v = fminf(v, __shfl_xor(v, 2, 64));
            v = fminf(v, __shfl_xor(v, 4, 64));
            v = fminf(v, __shfl_xor(v, 8, 64));
            vm = fmaxf(vm, v);
          }
          vml[mb][reg] = vm;
        }
      }
      __syncthreads();          // all LDS reads done; reuse As as pbuf
      float* pbuf = (float*)smem_raw;   // 128 floats
      if (wn == 1 && am == 0) {
#pragma unroll
        for (int mb = 0; mb < 4; ++mb)
#pragma unroll
          for (int reg = 0; reg < 4; ++reg)
            pbuf[wm * 64 + mb * 16 + quad * 4 + reg] = vml[mb][reg];
      }
      __syncthreads();
      if (wn == 0 && am == 0) {
#pragma unroll
        for (int mb = 0; mb < 4; ++mb)
#pragma unroll
          for (int reg = 0; reg < 4; ++reg) {
            const int ridx = wm * 64 + mb * 16 + quad * 4 + reg;
            const float v = fmaxf(vml[mb][reg], pbuf[ridx]);
            pmax[(size_t)(m0 + ridx) * 16 + nb] = v;
          }
      }
    }
  }
  __threadfence();
  grid.sync();

  // ---------------- phase 3: ybuf zero + margin test ------------------------
  {
    if (t < 192)
      ((float4*)ybuf)[(size_t)b * 192 + t] = (float4){0.f, 0.f, 0.f, 0.f};
    const int r3 = b * 16 + (t >> 4);
    float v = pmax[(size_t)r3 * 16 + (t & 15)];
    v = fmaxf(v, __shfl_xor(v, 1, 64));
    v = fmaxf(v, __shfl_xor(v, 2, 64));
    v = fmaxf(v, __shfl_xor(v, 4, 64));
    v = fmaxf(v, __shfl_xor(v, 8, 64));
    if ((t & 15) == 0) {
      const float u = rand_u[r3];
      const float slo = 1.0f / (1.0f + expf(-(v - MARGIN_EPS)));
      const float shi = 1.0f / (1.0f + expf(-(v + MARGIN_EPS)));
      if (u < slo) {
        out[r3] = 1.0f;
      } else if (u >= shi) {
        out[r3] = 0.0f;
      } else {
        const int i = atomicAdd(count, 1);
        if (i < 8192) undec[i] = r3;
      }
    }
  }
  __threadfence();
  grid.sync();

  // ---------------- phase 4: exact fp32 recompute (2 (g,kc)/block) ----------
  {
    int n = *count;
    if (n > MAX_UNDEC) n = MAX_UNDEC;
    if (n > 0) {
      float* wf = (float*)smem_raw;            // 64*129 floats = 33024 B
      float* part = wf + 64 * 129;             // 256 floats
      unsigned* msk = (unsigned*)(part + 256); // 64 uints
      if (t < 64) msk[t] = 0u;
      __syncthreads();
      for (int j = t; j < 512; j += 256) {
        const int c = montn[j];
        atomicOr(&msk[c >> 5], 1u << (c & 31));
      }
      __syncthreads();
#pragma unroll 1
      for (int pp = 0; pp < 2; ++pp) {
        const int idx = b + pp * 512;
        const int g = idx >> 4, kc = idx & 15;
        {  // stage W cols (montn-squared): thread t -> col t>>2, k-seg t&3
          const int cl = t >> 2, ks = t & 3;
          const int k0 = kc * 128 + ks * 32;
          const float* wp = wgt + (size_t)(g * 64 + cl) * 2048 + k0;
          float* dst = wf + cl * 129 + ks * 32;
          const unsigned mword = msk[k0 >> 5];
#pragma unroll
          for (int i = 0; i < 32; i += 4) {
            float4 wv = *(const float4*)(wp + i);
            float f0 = wv.x, f1 = wv.y, f2 = wv.z, f3 = wv.w;
            if ((mword >> (i + 0)) & 1u) f0 *= f0;
            if ((mword >> (i + 1)) & 1u) f1 *= f1;
            if ((mword >> (i + 2)) & 1u) f2 *= f2;
            if ((mword >> (i + 3)) & 1u) f3 *= f3;
            dst[i + 0] = f0; dst[i + 1] = f1; dst[i + 2] = f2; dst[i + 3] = f3;
          }
        }
        __syncthreads();
        const int col = t & 63, kq = t >> 6;
        const float* wcol = wf + col * 129 + kq * 32;
        for (int s = 0; s < n; ++s) {
          const int row = undec[s];
          const float* xp = x + (size_t)row * 2048 + kc * 128 + kq * 32;
          float acc = 0.f;
#pragma unroll
          for (int i = 0; i < 32; i += 4) {
            float4 xv = *(const float4*)(xp + i);
            acc = fmaf(xv.x, wcol[i + 0], acc);
            acc = fmaf(xv.y, wcol[i + 1], acc);
            acc = fmaf(xv.z, wcol[i + 2], acc);
            acc = fmaf(xv.w, wcol[i + 3], acc);
          }
          part[t] = acc;
          __syncthreads();
          if (t < 64) {
            const float y = part[t] + part[t + 64] + part[t + 128] +
                            part[t + 192];
            atomicAdd(ybuf + (size_t)s * 4096 + g * 64 + t, y);
          }
          __syncthreads();
        }
      }
    }
  }
  __threadfence();
  grid.sync();

  // ---------------- phase 5: decide undecided rows --------------------------
  {
    int n = *count;
    if (n > MAX_UNDEC) n = MAX_UNDEC;
    if (b < n) {
      float* gm = (float*)smem_raw;   // 64 floats
      const int s = b;
      const int g = t >> 2, p4 = t & 3;
      const float* yb = ybuf + (size_t)s * 4096;
      const int c0 = g * 64 + p4 * 16;
      float m = 3.4e38f;
#pragma unroll
      for (int e = 0; e < 16; ++e) m = fminf(m, yb[c0 + e] + bias[c0 + e]);
      m = fminf(m, __shfl_xor(m, 1, 64));
      m = fminf(m, __shfl_xor(m, 2, 64));
      if (p4 == 0) gm[g] = m;
      __syncthreads();
      if (t < 64) {
        float v = gm[t];
        v = fmaxf(v, __shfl_xor(v, 1, 64));
        v = fmaxf(v, __shfl_xor(v, 2, 64));
        v = fmaxf(v, __shfl_xor(v, 4, 64));
        v = fmaxf(v, __shfl_xor(v, 8, 64));
        v = fmaxf(v, __shfl_xor(v, 16, 64));
        v = fmaxf(v, __shfl_xor(v, 32, 64));
        if (t == 0) {
          const int row = undec[s];
          const float sg = 1.0f / (1.0f + expf(-v));
          out[row] = (rand_u[row] < sg) ? 1.0f : 0.0f;
        }
      }
    }
  }
}

// ===========================================================================
// R14 fallback chain (verified)
// ===========================================================================
__global__ void convert_split(float* __restrict__ x, float* __restrict__ wgt,
                              const int* __restrict__ montn,
                              int* __restrict__ count,
                              unsigned* __restrict__ gmax) {
  const int b = blockIdx.x;
  const int t = threadIdx.x;
  if (b >= 3072) {
    gmax[(b - 3072) * 256 + t] = 0u;
    return;
  }
  __shared__ unsigned msk[64];
  const int l = t & 63, w = t >> 6;
  const int r = b * 4 + w;
  const int use_mask = (r >= 8192) ? 1 : 0;
  if (b == 0 && t == 0) *count = 0;
  if (use_mask) {
    if (t < 64) msk[t] = 0u;
    __syncthreads();
    for (int j = t; j < 512; j += 256) {
      const int c = montn[j];
      atomicOr(&msk[c >> 5], 1u << (c & 31));
    }
    __syncthreads();
  }
  float* rowp = use_mask ? (wgt + (size_t)(r - 8192) * 2048)
                         : (x + (size_t)r * 2048);
  float4 v[4][2];
#pragma unroll
  for (int p = 0; p < 4; ++p) {
    v[p][0] = ((const float4*)rowp)[p * 128 + 2 * l];
    v[p][1] = ((const float4*)rowp)[p * 128 + 2 * l + 1];
  }
  unsigned mw[4];
#pragma unroll
  for (int p = 0; p < 4; ++p)
    mw[p] = use_mask ? msk[p * 16 + (l >> 2)] : 0u;

  unsigned short* up = (unsigned short*)rowp;
#pragma unroll
  for (int p = 0; p < 4; ++p) {
    float f[8];
    f[0] = v[p][0].x; f[1] = v[p][0].y; f[2] = v[p][0].z; f[3] = v[p][0].w;
    f[4] = v[p][1].x; f[5] = v[p][1].y; f[6] = v[p][1].z; f[7] = v[p][1].w;
    unsigned short hs[8], ls[8];
#pragma unroll
    for (int c = 0; c < 8; ++c) {
      float g = f[c];
      if ((mw[p] >> (8 * (l & 3) + c)) & 1u) g = g * g;
      _Float16 h = (_Float16)g;
      float res = g - (float)h;
      _Float16 lo = (_Float16)res;
      hs[c] = __builtin_bit_cast(unsigned short, h);
      ls[c] = __builtin_bit_cast(unsigned short, lo);
    }
    uint4 H, L;
    H.x = (unsigned)hs[0] | ((unsigned)hs[1] << 16);
    H.y = (unsigned)hs[2] | ((unsigned)hs[3] << 16);
    H.z = (unsigned)hs[4] | ((unsigned)hs[5] << 16);
    H.w = (unsigned)hs[6] | ((unsigned)hs[7] << 16);
    L.x = (unsigned)ls[0] | ((unsigned)ls[1] << 16);
    L.y = (unsigned)ls[2] | ((unsigned)ls[3] << 16);
    L.z = (unsigned)ls[4] | ((unsigned)ls[5] << 16);
    L.w = (unsigned)ls[6] | ((unsigned)ls[7] << 16);
    *((uint4*)(up + p * 512 + 8 * l)) = H;
    *((uint4*)(up + 2048 + p * 512 + 8 * l)) = L;
  }
}

__global__ __launch_bounds__(256, 2) void gemm_minmax(
    const unsigned short* __restrict__ X, const unsigned short* __restrict__ W,
    const float* __restrict__ bias, unsigned* __restrict__ gmax, int rs) {
  __shared__ unsigned short As[128 * 64];
  __shared__ unsigned short Bs[256 * 64];
  const int t = threadIdx.x;
  const int lane = t & 63;
  const int w = t >> 6;
  const int wm = w >> 1, wn = w & 1;
  const int lin = blockIdx.x;
  const int sid = lin >> 3;
  const int m0 = (sid >> 1) * 128;
  const int n0 = ((lin & 7) * 2 + (sid & 1)) * 256;

  const int rowBase = w * 8 + (lane >> 3);
  const int gchunk = ((lane & 7) ^ ((lane >> 3) & 7)) * 8;
  const size_t gA0 = (size_t)(m0 + rowBase) * rs + gchunk;
  const size_t gB0 = (size_t)(n0 + rowBase) * rs + gchunk;
  unsigned short* ldsA0 = As + w * 512;
  unsigned short* ldsB0 = Bs + w * 512;

  const int am = lane & 15, quad = lane >> 4;
  int arow[4], brow[8];
#pragma unroll
  for (int i = 0; i < 4; ++i) arow[i] = (wm * 64 + i * 16 + am) * 64;
#pragma unroll
  for (int j = 0; j < 8; ++j) brow[j] = (wn * 128 + j * 16 + am) * 64;
  int swz[2];
#pragma unroll
  for (int h = 0; h < 2; ++h) swz[h] = (((h << 2) + quad) ^ (am & 7)) * 8;

  f32x4 acc[4][8];
#pragma unroll
  for (int i = 0; i < 4; ++i)
#pragma unroll
    for (int j = 0; j < 8; ++j) acc[i][j] = (f32x4){0.f, 0.f, 0.f, 0.f};

#pragma unroll 1
  for (int it = 0; it < 32; ++it) {
    const int kin = it * 64;
    __syncthreads();
#pragma unroll
    for (int c = 0; c < 4; ++c)
      async_load16(X + gA0 + (size_t)(c * 32) * rs + kin, ldsA0 + c * 2048);
#pragma unroll
    for (int c = 0; c < 8; ++c)
      async_load16(W + gB0 + (size_t)(c * 32) * rs + kin, ldsB0 + c * 2048);
    __syncthreads();

#pragma unroll
    for (int h = 0; h < 2; ++h) {
      f16x8 av[4], bv[8];
#pragma unroll
      for (int i = 0; i < 4; ++i) av[i] = *(const f16x8*)(As + arow[i] + swz[h]);
#pragma unroll
      for (int j = 0; j < 8; ++j) bv[j] = *(const f16x8*)(Bs + brow[j] + swz[h]);
#pragma unroll
      for (int mb = 0; mb < 4; ++mb)
#pragma unroll
        for (int nb = 0; nb < 8; ++nb)
          acc[mb][nb] = __builtin_amdgcn_mfma_f32_16x16x32_f16(
              av[mb], bv[nb], acc[mb][nb], 0, 0, 0);
    }
  }

  float bv8[8];
#pragma unroll
  for (int nb = 0; nb < 8; ++nb) bv8[nb] = bias[n0 + wn * 128 + nb * 16 + am];
#pragma unroll
  for (int mb = 0; mb < 4; ++mb) {
#pragma unroll
    for (int reg = 0; reg < 4; ++reg) {
      float vm = -3.4e38f;
#pragma unroll
      for (int hh = 0; hh < 2; ++hh) {
        float v = fminf(
            fminf(acc[mb][4 * hh + 0][reg] + bv8[4 * hh + 0],
                  acc[mb][4 * hh + 1][reg] + bv8[4 * hh + 1]),
            fminf(acc[mb][4 * hh + 2][reg] + bv8[4 * hh + 2],
                  acc[mb][4 * hh + 3][reg] + bv8[4 * hh + 3]));
        v = fminf(v, __shfl_xor(v, 1, 64));
        v = fminf(v, __shfl_xor(v, 2, 64));
        v = fminf(v, __shfl_xor(v, 4, 64));
        v = fminf(v, __shfl_xor(v, 8, 64));
        vm = fmaxf(vm, v);
      }
      if (am == 0) {
        const int row = m0 + wm * 64 + mb * 16 + quad * 4 + reg;
        atomicMax(&gmax[row], f2key(vm));
      }
    }
  }
}

__global__ void finalize_margin(const unsigned* __restrict__ gmax,
                                const float* __restrict__ rand_u,
                                float* __restrict__ out,
                                int* __restrict__ count, int* __restrict__ undec,
                                float4* __restrict__ ybuf4) {
  const int t = threadIdx.x;
  ybuf4[(size_t)blockIdx.x * 256 + t] = (float4){0.f, 0.f, 0.f, 0.f};
  if (blockIdx.x < 32) {
    const int row = blockIdx.x * 256 + t;
    const float v = key2f(gmax[row]);
    const float u = rand_u[row];
    const float slo = 1.0f / (1.0f + expf(-(v - MARGIN_EPS)));
    const float shi = 1.0f / (1.0f + expf(-(v + MARGIN_EPS)));
    if (u < slo) {
      out[row] = 1.0f;
    } else if (u >= shi) {
      out[row] = 0.0f;
    } else {
      const int i = atomicAdd(count, 1);
      if (i < 8192) undec[i] = row;
    }
  }
}

__global__ __launch_bounds__(256) void recompute_rows(
    const unsigned short* __restrict__ X, const unsigned short* __restrict__ W,
    const int* __restrict__ count, const int* __restrict__ undec,
    float* __restrict__ ybuf) {
  __shared__ float wf[64 * 129];
  __shared__ float part[256];
  const int g = blockIdx.x, kc = blockIdx.y;
  const int t = threadIdx.x;
  int n = *count;
  if (n > MAX_UNDEC) n = MAX_UNDEC;
  if (n == 0) return;

  {
    const int cl = t >> 2, ks = t & 3;
    const unsigned short* wp =
        W + (size_t)(g * 64 + cl) * 4096 + kc * 128 + ks * 32;
    float* dst = wf + cl * 129 + ks * 32;
#pragma unroll
    for (int i = 0; i < 32; i += 8) {
      uint4 hv = *(const uint4*)(wp + i);
      uint4 lv = *(const uint4*)(wp + 2048 + i);
      const unsigned* hw = (const unsigned*)&hv;
      const unsigned* lw = (const unsigned*)&lv;
#pragma unroll
      for (int m = 0; m < 4; ++m) {
        dst[i + 2 * m] = us2f((unsigned short)(hw[m] & 0xFFFF)) +
                         us2f((unsigned short)(lw[m] & 0xFFFF));
        dst[i + 2 * m + 1] = us2f((unsigned short)(hw[m] >> 16)) +
                             us2f((unsigned short)(lw[m] >> 16));
      }
    }
  }
  __syncthreads();

  const int col = t & 63, kq = t >> 6;
  const float* wcol = wf + col * 129 + kq * 32;
  for (int s = 0; s < n; ++s) {
    const int row = undec[s];
    const unsigned short* xp = X + (size_t)row * 4096 + kc * 128 + kq * 32;
    float acc = 0.f;
#pragma unroll
    for (int i = 0; i < 32; i += 8) {
      uint4 hv = *(const uint4*)(xp + i);
      uint4 lv = *(const uint4*)(xp + 2048 + i);
      const unsigned* hw = (const unsigned*)&hv;
      const unsigned* lw = (const unsigned*)&lv;
#pragma unroll
      for (int m = 0; m < 4; ++m) {
        const float x0 = us2f((unsigned short)(hw[m] & 0xFFFF)) +
                         us2f((unsigned short)(lw[m] & 0xFFFF));
        const float x1 = us2f((unsigned short)(hw[m] >> 16)) +
                         us2f((unsigned short)(lw[m] >> 16));
        acc = fmaf(x0, wcol[i + 2 * m], acc);
        acc = fmaf(x1, wcol[i + 2 * m + 1], acc);
      }
    }
    part[t] = acc;
    __syncthreads();
    if (t < 64) {
      const float y = part[t] + part[t + 64] + part[t + 128] + part[t + 192];
      atomicAdd(ybuf + (size_t)s * 4096 + g * 64 + t, y);
    }
    __syncthreads();
  }
}

__global__ void decide(const float* __restrict__ ybuf,
                       const int* __restrict__ undec, const int* __restrict__ count,
                       const float* __restrict__ bias,
                       const float* __restrict__ rand_u, float* __restrict__ out) {
  __shared__ float gm[64];
  int n = *count;
  if (n > MAX_UNDEC) n = MAX_UNDEC;
  const int s = blockIdx.x;
  if (s >= n) return;
  const int t = threadIdx.x;
  const int g = t >> 2, p4 = t & 3;
  const float* yb = ybuf + (size_t)s * 4096;
  const int c0 = g * 64 + p4 * 16;
  float m = 3.4e38f;
#pragma unroll
  for (int e = 0; e < 16; ++e) m = fminf(m, yb[c0 + e] + bias[c0 + e]);
  m = fminf(m, __shfl_xor(m, 1, 64));
  m = fminf(m, __shfl_xor(m, 2, 64));
  if (p4 == 0) gm[g] = m;
  __syncthreads();
  if (t < 64) {
    float v = gm[t];
    v = fmaxf(v, __shfl_xor(v, 1, 64));
    v = fmaxf(v, __shfl_xor(v, 2, 64));
    v = fmaxf(v, __shfl_xor(v, 4, 64));
    v = fmaxf(v, __shfl_xor(v, 8, 64));
    v = fmaxf(v, __shfl_xor(v, 16, 64));
    v = fmaxf(v, __shfl_xor(v, 32, 64));
    if (t == 0) {
      const int row = undec[s];
      const float sg = 1.0f / (1.0f + expf(-v));
      out[row] = (rand_u[row] < sg) ? 1.0f : 0.0f;
    }
  }
}

extern "C" void kernel_launch(void* const* d_in, const int* in_sizes, int n_in,
                              void* d_out, int out_size, void* d_ws, size_t ws_size,
                              hipStream_t stream) {
  float* x = (float*)d_in[0];           // [8192, 2048] fp32
  float* weight = (float*)d_in[1];      // [4096, 2048] fp32
  const float* bias = (const float*)d_in[2];
  const float* rand_u = (const float*)d_in[3];
  const int* montn = (const int*)d_in[4];
  float* out = (float*)d_out;

  char* ws = (char*)d_ws;
  int* count = (int*)ws;                              // 4 B
  int* undec = (int*)(ws + 256);                      // 32 KB
  float* ybuf = (float*)(ws + 65536);                 // 1.5 MB
  float* pmax = (float*)(ws + 65536 + 1572864);       // 512 KB [8192][16]
  unsigned* gmax = (unsigned*)(ws + 65536 + 1572864); // fallback reuse (32 KB)

  const size_t XO_OFF = (size_t)4 * 1024 * 1024;
  const size_t XO_BYTES = (size_t)8192 * 2048 * 2;
  const size_t WO_BYTES = (size_t)4096 * 2048 * 2;
  const bool big_ws = ws_size >= XO_OFF + XO_BYTES + WO_BYTES;

  hipError_t cerr = hipErrorUnknown;
  if (big_ws) {
    unsigned short* xo = (unsigned short*)(ws + XO_OFF);
    unsigned short* wo = (unsigned short*)(ws + XO_OFF + XO_BYTES);
    const float* biasp = bias;
    const float* randp = rand_u;
    const int* montnp = montn;
    void* args[] = {(void*)&x,     (void*)&weight, (void*)&biasp,
                    (void*)&randp, (void*)&montnp, (void*)&out,
                    (void*)&xo,    (void*)&wo,     (void*)&count,
                    (void*)&undec, (void*)&ybuf,   (void*)&pmax};
    cerr = hipLaunchCooperativeKernel((const void*)fused_all, dim3(512),
                                      dim3(256), args, 0, stream);
  }
  if (cerr != hipSuccess) {
    (void)hipGetLastError();   // clear any sticky error from the attempt
    convert_split<<<3104, 256, 0, stream>>>(x, weight, montn, count, gmax);
    gemm_minmax<<<1024, 256, 0, stream>>>(
        (const unsigned short*)x, (const unsigned short*)weight, bias, gmax,
        4096);
    finalize_margin<<<384, 256, 0, stream>>>(gmax, rand_u, out, count, undec,
                                             (float4*)ybuf);
    recompute_rows<<<dim3(64, 16), 256, 0, stream>>>(
        (const unsigned short*)x, (const unsigned short*)weight, count, undec,
        ybuf);
    decide<<<MAX_UNDEC, 256, 0, stream>>>(ybuf, undec, count, bias, rand_u,
                                          out);
  }
}

// Round 7
// 296.346 us; speedup vs baseline: 2.3747x; 2.3747x over previous
//
#include <hip/hip_runtime.h>
#include <cmath>

// ---------------------------------------------------------------------------
// min_max_net: w' = weight with montn columns squared; y = x @ w'^T + bias;
// out[b] = (rand_u[b] < sigmoid(max_g min_{j in g} y[b, g*64+j])) ? 1 : 0
//
// R16: R14 chain (coop fusion refuted: grid.sync across non-coherent XCD L2s
// cost +420us). Atomic elimination:
//  - gemm: R15-verified LDS-combine epilogue -> plain stores to pmax[8192][16]
//    (R13 measured plain-store gemm at 126.6us vs R14 atomicMax 131us).
//  - recompute: partial writes ypart[kc][s][col] (each cell written once; no
//    atomics, no ybuf zeroing). ypart aliases xo (dead after gemm).
//  - finalize: 32 blocks, reads pmax only.
//  - decide: sums 16 kc-partials, coalesced; wave-structured min/max reduce.
// Fallback (small ws): R14 chain verbatim (_fb kernels).
// ---------------------------------------------------------------------------

typedef _Float16 f16x8 __attribute__((ext_vector_type(8)));
typedef float f32x4 __attribute__((ext_vector_type(4)));

#define MARGIN_EPS 4e-3f
#define MAX_UNDEC 96

__device__ __forceinline__ void async_load16(const void* gptr, void* lptr) {
  __builtin_amdgcn_global_load_lds(
      (const __attribute__((address_space(1))) void*)gptr,
      (__attribute__((address_space(3))) void*)lptr, 16, 0, 0);
}

__device__ __forceinline__ float us2f(unsigned short u) {
  return (float)__builtin_bit_cast(_Float16, u);
}

// order-preserving float -> uint key (fallback path only)
__device__ __forceinline__ unsigned f2key(float f) {
  unsigned b = __float_as_uint(f);
  return (b & 0x80000000u) ? ~b : (b | 0x80000000u);
}
__device__ __forceinline__ float key2f(unsigned e) {
  unsigned b = (e & 0x80000000u) ? (e ^ 0x80000000u) : ~e;
  return __uint_as_float(b);
}

// ===========================================================================
// big-ws path
// ===========================================================================

// ---- kernel 1: fp32 row -> hi fp16 compact (stride 2048), 1 wave per row ---
__global__ void convert_hi(const float* __restrict__ x,
                           const float* __restrict__ wgt,
                           unsigned short* __restrict__ xo,
                           unsigned short* __restrict__ wo,
                           const int* __restrict__ montn,
                           int* __restrict__ count) {
  __shared__ unsigned msk[64];
  const int b = blockIdx.x, t = threadIdx.x;
  const int l = t & 63, w = t >> 6;
  const int r = b * 4 + w;
  const int use_mask = (r >= 8192) ? 1 : 0;   // block-uniform (4-row blocks)
  if (b == 0 && t == 0) *count = 0;
  if (use_mask) {
    if (t < 64) msk[t] = 0u;
    __syncthreads();
    for (int j = t; j < 512; j += 256) {
      const int c = montn[j];
      atomicOr(&msk[c >> 5], 1u << (c & 31));
    }
    __syncthreads();
  }
  const float* rowp = use_mask ? (wgt + (size_t)(r - 8192) * 2048)
                               : (x + (size_t)r * 2048);
  unsigned short* up = use_mask ? (wo + (size_t)(r - 8192) * 2048)
                                : (xo + (size_t)r * 2048);
  float4 v[4][2];
#pragma unroll
  for (int p = 0; p < 4; ++p) {
    v[p][0] = ((const float4*)rowp)[p * 128 + 2 * l];
    v[p][1] = ((const float4*)rowp)[p * 128 + 2 * l + 1];
  }
  unsigned mw[4];
#pragma unroll
  for (int p = 0; p < 4; ++p)
    mw[p] = use_mask ? msk[p * 16 + (l >> 2)] : 0u;

#pragma unroll
  for (int p = 0; p < 4; ++p) {
    float f[8];
    f[0] = v[p][0].x; f[1] = v[p][0].y; f[2] = v[p][0].z; f[3] = v[p][0].w;
    f[4] = v[p][1].x; f[5] = v[p][1].y; f[6] = v[p][1].z; f[7] = v[p][1].w;
    unsigned short hs[8];
#pragma unroll
    for (int c = 0; c < 8; ++c) {
      float g = f[c];
      if ((mw[p] >> (8 * (l & 3) + c)) & 1u) g = g * g;
      hs[c] = __builtin_bit_cast(unsigned short, (_Float16)g);   // RTNE
    }
    uint4 H;
    H.x = (unsigned)hs[0] | ((unsigned)hs[1] << 16);
    H.y = (unsigned)hs[2] | ((unsigned)hs[3] << 16);
    H.z = (unsigned)hs[4] | ((unsigned)hs[5] << 16);
    H.w = (unsigned)hs[6] | ((unsigned)hs[7] << 16);
    *((uint4*)(up + p * 512 + 8 * l)) = H;
  }
}

// ---- kernel 2: hi*hi GEMM + fused bias/group-min, plain pmax stores --------
// R9 verified loop body; R15-verified LDS-combine epilogue (no atomics).
__global__ __launch_bounds__(256, 2) void gemm_minmax(
    const unsigned short* __restrict__ X, const unsigned short* __restrict__ W,
    const float* __restrict__ bias, float* __restrict__ pmax) {
  __shared__ unsigned short As[128 * 64];   // 16 KB
  __shared__ unsigned short Bs[256 * 64];   // 32 KB
  const int t = threadIdx.x;
  const int lane = t & 63;
  const int w = t >> 6;
  const int wm = w >> 1, wn = w & 1;
  const int lin = blockIdx.x;
  const int sid = lin >> 3;
  const int m0 = (sid >> 1) * 128;
  const int nb = (lin & 7) * 2 + (sid & 1);
  const int n0 = nb * 256;

  const int rowBase = w * 8 + (lane >> 3);
  const int gchunk = ((lane & 7) ^ ((lane >> 3) & 7)) * 8;  // ushort offset
  const size_t gA0 = (size_t)(m0 + rowBase) * 2048 + gchunk;
  const size_t gB0 = (size_t)(n0 + rowBase) * 2048 + gchunk;
  unsigned short* ldsA0 = As + w * 512;
  unsigned short* ldsB0 = Bs + w * 512;

  const int am = lane & 15, quad = lane >> 4;
  int arow[4], brow[8];
#pragma unroll
  for (int i = 0; i < 4; ++i) arow[i] = (wm * 64 + i * 16 + am) * 64;
#pragma unroll
  for (int j = 0; j < 8; ++j) brow[j] = (wn * 128 + j * 16 + am) * 64;
  int swz[2];
#pragma unroll
  for (int h = 0; h < 2; ++h) swz[h] = (((h << 2) + quad) ^ (am & 7)) * 8;

  f32x4 acc[4][8];
#pragma unroll
  for (int i = 0; i < 4; ++i)
#pragma unroll
    for (int j = 0; j < 8; ++j) acc[i][j] = (f32x4){0.f, 0.f, 0.f, 0.f};

#pragma unroll 1
  for (int it = 0; it < 32; ++it) {
    const int kin = it * 64;
    __syncthreads();  // previous iteration's LDS reads complete
#pragma unroll
    for (int c = 0; c < 4; ++c)
      async_load16(X + gA0 + (size_t)(c * 32) * 2048 + kin, ldsA0 + c * 2048);
#pragma unroll
    for (int c = 0; c < 8; ++c)
      async_load16(W + gB0 + (size_t)(c * 32) * 2048 + kin, ldsB0 + c * 2048);
    __syncthreads();  // staging complete (drains vmcnt)

#pragma unroll
    for (int h = 0; h < 2; ++h) {
      f16x8 av[4], bv[8];
#pragma unroll
      for (int i = 0; i < 4; ++i) av[i] = *(const f16x8*)(As + arow[i] + swz[h]);
#pragma unroll
      for (int j = 0; j < 8; ++j) bv[j] = *(const f16x8*)(Bs + brow[j] + swz[h]);
#pragma unroll
      for (int mb = 0; mb < 4; ++mb)
#pragma unroll
        for (int nb8 = 0; nb8 < 8; ++nb8)
          acc[mb][nb8] = __builtin_amdgcn_mfma_f32_16x16x32_f16(
              av[mb], bv[nb8], acc[mb][nb8], 0, 0, 0);
    }
  }

  // epilogue: bias + per-group (64-col) min; max over this block's 4 groups;
  // combine the two wn-waves via LDS; ONE plain store per (row, nb).
  float bv8[8];
#pragma unroll
  for (int nb8 = 0; nb8 < 8; ++nb8)
    bv8[nb8] = bias[n0 + wn * 128 + nb8 * 16 + am];
  float vml[4][4];
#pragma unroll
  for (int mb = 0; mb < 4; ++mb) {
#pragma unroll
    for (int reg = 0; reg < 4; ++reg) {
      float vm = -3.4e38f;
#pragma unroll
      for (int hh = 0; hh < 2; ++hh) {
        float v = fminf(
            fminf(acc[mb][4 * hh + 0][reg] + bv8[4 * hh + 0],
                  acc[mb][4 * hh + 1][reg] + bv8[4 * hh + 1]),
            fminf(acc[mb][4 * hh + 2][reg] + bv8[4 * hh + 2],
                  acc[mb][4 * hh + 3][reg] + bv8[4 * hh + 3]));
        v = fminf(v, __shfl_xor(v, 1, 64));
        v = fminf(v, __shfl_xor(v, 2, 64));
        v = fminf(v, __shfl_xor(v, 4, 64));
        v = fminf(v, __shfl_xor(v, 8, 64));
        vm = fmaxf(vm, v);
      }
      vml[mb][reg] = vm;
    }
  }
  __syncthreads();                   // all LDS reads done; reuse As as pbuf
  float* pbuf = (float*)As;          // 128 floats
  if (wn == 1 && am == 0) {
#pragma unroll
    for (int mb = 0; mb < 4; ++mb)
#pragma unroll
      for (int reg = 0; reg < 4; ++reg)
        pbuf[wm * 64 + mb * 16 + quad * 4 + reg] = vml[mb][reg];
  }
  __syncthreads();
  if (wn == 0 && am == 0) {
#pragma unroll
    for (int mb = 0; mb < 4; ++mb)
#pragma unroll
      for (int reg = 0; reg < 4; ++reg) {
        const int ridx = wm * 64 + mb * 16 + quad * 4 + reg;
        pmax[(size_t)(m0 + ridx) * 16 + nb] = fmaxf(vml[mb][reg], pbuf[ridx]);
      }
  }
}

// ---- kernel 3: margin test from pmax, 32 blocks ----------------------------
__global__ void finalize_margin(const float* __restrict__ pmax,
                                const float* __restrict__ rand_u,
                                float* __restrict__ out,
                                int* __restrict__ count,
                                int* __restrict__ undec) {
  const int row = blockIdx.x * 256 + threadIdx.x;
  const float4* pp = (const float4*)(pmax + (size_t)row * 16);
  const float4 a = pp[0], b4 = pp[1], c4 = pp[2], d4 = pp[3];
  float v = fmaxf(fmaxf(fmaxf(a.x, a.y), fmaxf(a.z, a.w)),
                  fmaxf(fmaxf(b4.x, b4.y), fmaxf(b4.z, b4.w)));
  v = fmaxf(v, fmaxf(fmaxf(c4.x, c4.y), fmaxf(c4.z, c4.w)));
  v = fmaxf(v, fmaxf(fmaxf(d4.x, d4.y), fmaxf(d4.z, d4.w)));
  const float u = rand_u[row];
  const float slo = 1.0f / (1.0f + expf(-(v - MARGIN_EPS)));
  const float shi = 1.0f / (1.0f + expf(-(v + MARGIN_EPS)));
  if (u < slo) {
    out[row] = 1.0f;
  } else if (u >= shi) {
    out[row] = 0.0f;
  } else {
    const int i = atomicAdd(count, 1);
    if (i < 8192) undec[i] = row;
  }
}

// ---- kernel 4: exact fp32 recompute from ORIGINALS, partial writes ---------
// block (g, kc) writes ypart[kc][s][g*64 + col] -- each cell exactly once.
__global__ __launch_bounds__(256) void recompute_fp32(
    const float* __restrict__ X, const float* __restrict__ W,
    const int* __restrict__ montn, const int* __restrict__ count,
    const int* __restrict__ undec, float* __restrict__ ypart) {
  __shared__ float wf[64 * 129];   // ~33 KB
  __shared__ float part[256];
  __shared__ unsigned msk[64];
  const int g = blockIdx.x, kc = blockIdx.y;
  const int t = threadIdx.x;
  int n = *count;
  if (n > MAX_UNDEC) n = MAX_UNDEC;
  if (n == 0) return;

  if (t < 64) msk[t] = 0u;
  __syncthreads();
  for (int j = t; j < 512; j += 256) {
    const int c = montn[j];
    atomicOr(&msk[c >> 5], 1u << (c & 31));
  }
  __syncthreads();

  {  // stage W cols (montn-squared): thread t -> col t>>2, k-seg t&3 (32 k)
    const int cl = t >> 2, ks = t & 3;
    const int k0 = kc * 128 + ks * 32;
    const float* wp = W + (size_t)(g * 64 + cl) * 2048 + k0;
    float* dst = wf + cl * 129 + ks * 32;
    const unsigned mword = msk[k0 >> 5];   // k0 32-aligned: one word covers
#pragma unroll
    for (int i = 0; i < 32; i += 4) {
      float4 wv = *(const float4*)(wp + i);
      float f0 = wv.x, f1 = wv.y, f2 = wv.z, f3 = wv.w;
      if ((mword >> (i + 0)) & 1u) f0 *= f0;
      if ((mword >> (i + 1)) & 1u) f1 *= f1;
      if ((mword >> (i + 2)) & 1u) f2 *= f2;
      if ((mword >> (i + 3)) & 1u) f3 *= f3;
      dst[i + 0] = f0; dst[i + 1] = f1; dst[i + 2] = f2; dst[i + 3] = f3;
    }
  }
  __syncthreads();

  const int col = t & 63, kq = t >> 6;   // 32 k per quarter
  const float* wcol = wf + col * 129 + kq * 32;
  float* yout = ypart + (size_t)kc * (96 * 4096);
  for (int s = 0; s < n; ++s) {
    const int row = undec[s];
    const float* xp = X + (size_t)row * 2048 + kc * 128 + kq * 32;
    float acc = 0.f;
#pragma unroll
    for (int i = 0; i < 32; i += 4) {
      float4 xv = *(const float4*)(xp + i);
      acc = fmaf(xv.x, wcol[i + 0], acc);
      acc = fmaf(xv.y, wcol[i + 1], acc);
      acc = fmaf(xv.z, wcol[i + 2], acc);
      acc = fmaf(xv.w, wcol[i + 3], acc);
    }
    part[t] = acc;
    __syncthreads();
    if (t < 64) {
      const float yv = part[t] + part[t + 64] + part[t + 128] + part[t + 192];
      yout[(size_t)s * 4096 + g * 64 + t] = yv;     // plain store, no atomic
    }
    __syncthreads();
  }
}

// ---- kernel 5: decide -- sum 16 kc-partials, wave-structured reduce --------
// thread t covers cols {t + 256e}: for fixed e, wave w's 64 lanes hold
// exactly group g = w + 4e -> wave min-reduce -> gm[g]; then max over 64.
__global__ void decide(const float* __restrict__ ypart,
                       const int* __restrict__ undec,
                       const int* __restrict__ count,
                       const float* __restrict__ bias,
                       const float* __restrict__ rand_u,
                       float* __restrict__ out) {
  __shared__ float gm[64];
  int n = *count;
  if (n > MAX_UNDEC) n = MAX_UNDEC;
  const int s = blockIdx.x;
  if (s >= n) return;
  const int t = threadIdx.x, w = t >> 6;
  const float* yb = ypart + (size_t)s * 4096;
#pragma unroll 1
  for (int e = 0; e < 16; ++e) {
    const int c = t + e * 256;
    float y = bias[c];
#pragma unroll
    for (int kc = 0; kc < 16; ++kc)
      y += yb[(size_t)kc * (96 * 4096) + c];
    y = fminf(y, __shfl_xor(y, 1, 64));
    y = fminf(y, __shfl_xor(y, 2, 64));
    y = fminf(y, __shfl_xor(y, 4, 64));
    y = fminf(y, __shfl_xor(y, 8, 64));
    y = fminf(y, __shfl_xor(y, 16, 64));
    y = fminf(y, __shfl_xor(y, 32, 64));
    if ((t & 63) == 0) gm[w + 4 * e] = y;
  }
  __syncthreads();
  if (t < 64) {
    float v = gm[t];
    v = fmaxf(v, __shfl_xor(v, 1, 64));
    v = fmaxf(v, __shfl_xor(v, 2, 64));
    v = fmaxf(v, __shfl_xor(v, 4, 64));
    v = fmaxf(v, __shfl_xor(v, 8, 64));
    v = fmaxf(v, __shfl_xor(v, 16, 64));
    v = fmaxf(v, __shfl_xor(v, 32, 64));
    if (t == 0) {
      const int row = undec[s];
      const float sg = 1.0f / (1.0f + expf(-v));
      out[row] = (rand_u[row] < sg) ? 1.0f : 0.0f;
    }
  }
}

// ===========================================================================
// R14 fallback chain (verified), small-ws only
// ===========================================================================
__global__ void convert_split_fb(float* __restrict__ x, float* __restrict__ wgt,
                                 const int* __restrict__ montn,
                                 int* __restrict__ count,
                                 unsigned* __restrict__ gmax) {
  const int b = blockIdx.x;
  const int t = threadIdx.x;
  if (b >= 3072) {
    gmax[(b - 3072) * 256 + t] = 0u;
    return;
  }
  __shared__ unsigned msk[64];
  const int l = t & 63, w = t >> 6;
  const int r = b * 4 + w;
  const int use_mask = (r >= 8192) ? 1 : 0;
  if (b == 0 && t == 0) *count = 0;
  if (use_mask) {
    if (t < 64) msk[t] = 0u;
    __syncthreads();
    for (int j = t; j < 512; j += 256) {
      const int c = montn[j];
      atomicOr(&msk[c >> 5], 1u << (c & 31));
    }
    __syncthreads();
  }
  float* rowp = use_mask ? (wgt + (size_t)(r - 8192) * 2048)
                         : (x + (size_t)r * 2048);
  float4 v[4][2];
#pragma unroll
  for (int p = 0; p < 4; ++p) {
    v[p][0] = ((const float4*)rowp)[p * 128 + 2 * l];
    v[p][1] = ((const float4*)rowp)[p * 128 + 2 * l + 1];
  }
  unsigned mw[4];
#pragma unroll
  for (int p = 0; p < 4; ++p)
    mw[p] = use_mask ? msk[p * 16 + (l >> 2)] : 0u;

  unsigned short* up = (unsigned short*)rowp;
#pragma unroll
  for (int p = 0; p < 4; ++p) {
    float f[8];
    f[0] = v[p][0].x; f[1] = v[p][0].y; f[2] = v[p][0].z; f[3] = v[p][0].w;
    f[4] = v[p][1].x; f[5] = v[p][1].y; f[6] = v[p][1].z; f[7] = v[p][1].w;
    unsigned short hs[8], ls[8];
#pragma unroll
    for (int c = 0; c < 8; ++c) {
      float g = f[c];
      if ((mw[p] >> (8 * (l & 3) + c)) & 1u) g = g * g;
      _Float16 h = (_Float16)g;
      float res = g - (float)h;
      _Float16 lo = (_Float16)res;
      hs[c] = __builtin_bit_cast(unsigned short, h);
      ls[c] = __builtin_bit_cast(unsigned short, lo);
    }
    uint4 H, L;
    H.x = (unsigned)hs[0] | ((unsigned)hs[1] << 16);
    H.y = (unsigned)hs[2] | ((unsigned)hs[3] << 16);
    H.z = (unsigned)hs[4] | ((unsigned)hs[5] << 16);
    H.w = (unsigned)hs[6] | ((unsigned)hs[7] << 16);
    L.x = (unsigned)ls[0] | ((unsigned)ls[1] << 16);
    L.y = (unsigned)ls[2] | ((unsigned)ls[3] << 16);
    L.z = (unsigned)ls[4] | ((unsigned)ls[5] << 16);
    L.w = (unsigned)ls[6] | ((unsigned)ls[7] << 16);
    *((uint4*)(up + p * 512 + 8 * l)) = H;
    *((uint4*)(up + 2048 + p * 512 + 8 * l)) = L;
  }
}

__global__ __launch_bounds__(256, 2) void gemm_minmax_fb(
    const unsigned short* __restrict__ X, const unsigned short* __restrict__ W,
    const float* __restrict__ bias, unsigned* __restrict__ gmax) {
  __shared__ unsigned short As[128 * 64];
  __shared__ unsigned short Bs[256 * 64];
  const int t = threadIdx.x;
  const int lane = t & 63;
  const int w = t >> 6;
  const int wm = w >> 1, wn = w & 1;
  const int lin = blockIdx.x;
  const int sid = lin >> 3;
  const int m0 = (sid >> 1) * 128;
  const int n0 = ((lin & 7) * 2 + (sid & 1)) * 256;

  const int rowBase = w * 8 + (lane >> 3);
  const int gchunk = ((lane & 7) ^ ((lane >> 3) & 7)) * 8;
  const size_t gA0 = (size_t)(m0 + rowBase) * 4096 + gchunk;
  const size_t gB0 = (size_t)(n0 + rowBase) * 4096 + gchunk;
  unsigned short* ldsA0 = As + w * 512;
  unsigned short* ldsB0 = Bs + w * 512;

  const int am = lane & 15, quad = lane >> 4;
  int arow[4], brow[8];
#pragma unroll
  for (int i = 0; i < 4; ++i) arow[i] = (wm * 64 + i * 16 + am) * 64;
#pragma unroll
  for (int j = 0; j < 8; ++j) brow[j] = (wn * 128 + j * 16 + am) * 64;
  int swz[2];
#pragma unroll
  for (int h = 0; h < 2; ++h) swz[h] = (((h << 2) + quad) ^ (am & 7)) * 8;

  f32x4 acc[4][8];
#pragma unroll
  for (int i = 0; i < 4; ++i)
#pragma unroll
    for (int j = 0; j < 8; ++j) acc[i][j] = (f32x4){0.f, 0.f, 0.f, 0.f};

#pragma unroll 1
  for (int it = 0; it < 32; ++it) {
    const int kin = it * 64;
    __syncthreads();
#pragma unroll
    for (int c = 0; c < 4; ++c)
      async_load16(X + gA0 + (size_t)(c * 32) * 4096 + kin, ldsA0 + c * 2048);
#pragma unroll
    for (int c = 0; c < 8; ++c)
      async_load16(W + gB0 + (size_t)(c * 32) * 4096 + kin, ldsB0 + c * 2048);
    __syncthreads();

#pragma unroll
    for (int h = 0; h < 2; ++h) {
      f16x8 av[4], bv[8];
#pragma unroll
      for (int i = 0; i < 4; ++i) av[i] = *(const f16x8*)(As + arow[i] + swz[h]);
#pragma unroll
      for (int j = 0; j < 8; ++j) bv[j] = *(const f16x8*)(Bs + brow[j] + swz[h]);
#pragma unroll
      for (int mb = 0; mb < 4; ++mb)
#pragma unroll
        for (int nb = 0; nb < 8; ++nb)
          acc[mb][nb] = __builtin_amdgcn_mfma_f32_16x16x32_f16(
              av[mb], bv[nb], acc[mb][nb], 0, 0, 0);
    }
  }

  float bv8[8];
#pragma unroll
  for (int nb = 0; nb < 8; ++nb) bv8[nb] = bias[n0 + wn * 128 + nb * 16 + am];
#pragma unroll
  for (int mb = 0; mb < 4; ++mb) {
#pragma unroll
    for (int reg = 0; reg < 4; ++reg) {
      float vm = -3.4e38f;
#pragma unroll
      for (int hh = 0; hh < 2; ++hh) {
        float v = fminf(
            fminf(acc[mb][4 * hh + 0][reg] + bv8[4 * hh + 0],
                  acc[mb][4 * hh + 1][reg] + bv8[4 * hh + 1]),
            fminf(acc[mb][4 * hh + 2][reg] + bv8[4 * hh + 2],
                  acc[mb][4 * hh + 3][reg] + bv8[4 * hh + 3]));
        v = fminf(v, __shfl_xor(v, 1, 64));
        v = fminf(v, __shfl_xor(v, 2, 64));
        v = fminf(v, __shfl_xor(v, 4, 64));
        v = fminf(v, __shfl_xor(v, 8, 64));
        vm = fmaxf(vm, v);
      }
      if (am == 0) {
        const int row = m0 + wm * 64 + mb * 16 + quad * 4 + reg;
        atomicMax(&gmax[row], f2key(vm));
      }
    }
  }
}

__global__ void finalize_margin_fb(const unsigned* __restrict__ gmax,
                                   const float* __restrict__ rand_u,
                                   float* __restrict__ out,
                                   int* __restrict__ count,
                                   int* __restrict__ undec,
                                   float4* __restrict__ ybuf4) {
  const int t = threadIdx.x;
  ybuf4[(size_t)blockIdx.x * 256 + t] = (float4){0.f, 0.f, 0.f, 0.f};
  if (blockIdx.x < 32) {
    const int row = blockIdx.x * 256 + t;
    const float v = key2f(gmax[row]);
    const float u = rand_u[row];
    const float slo = 1.0f / (1.0f + expf(-(v - MARGIN_EPS)));
    const float shi = 1.0f / (1.0f + expf(-(v + MARGIN_EPS)));
    if (u < slo) {
      out[row] = 1.0f;
    } else if (u >= shi) {
      out[row] = 0.0f;
    } else {
      const int i = atomicAdd(count, 1);
      if (i < 8192) undec[i] = row;
    }
  }
}

__global__ __launch_bounds__(256) void recompute_rows_fb(
    const unsigned short* __restrict__ X, const unsigned short* __restrict__ W,
    const int* __restrict__ count, const int* __restrict__ undec,
    float* __restrict__ ybuf) {
  __shared__ float wf[64 * 129];
  __shared__ float part[256];
  const int g = blockIdx.x, kc = blockIdx.y;
  const int t = threadIdx.x;
  int n = *count;
  if (n > MAX_UNDEC) n = MAX_UNDEC;
  if (n == 0) return;

  {
    const int cl = t >> 2, ks = t & 3;
    const unsigned short* wp =
        W + (size_t)(g * 64 + cl) * 4096 + kc * 128 + ks * 32;
    float* dst = wf + cl * 129 + ks * 32;
#pragma unroll
    for (int i = 0; i < 32; i += 8) {
      uint4 hv = *(const uint4*)(wp + i);
      uint4 lv = *(const uint4*)(wp + 2048 + i);
      const unsigned* hw = (const unsigned*)&hv;
      const unsigned* lw = (const unsigned*)&lv;
#pragma unroll
      for (int m = 0; m < 4; ++m) {
        dst[i + 2 * m] = us2f((unsigned short)(hw[m] & 0xFFFF)) +
                         us2f((unsigned short)(lw[m] & 0xFFFF));
        dst[i + 2 * m + 1] = us2f((unsigned short)(hw[m] >> 16)) +
                             us2f((unsigned short)(lw[m] >> 16));
      }
    }
  }
  __syncthreads();

  const int col = t & 63, kq = t >> 6;
  const float* wcol = wf + col * 129 + kq * 32;
  for (int s = 0; s < n; ++s) {
    const int row = undec[s];
    const unsigned short* xp = X + (size_t)row * 4096 + kc * 128 + kq * 32;
    float acc = 0.f;
#pragma unroll
    for (int i = 0; i < 32; i += 8) {
      uint4 hv = *(const uint4*)(xp + i);
      uint4 lv = *(const uint4*)(xp + 2048 + i);
      const unsigned* hw = (const unsigned*)&hv;
      const unsigned* lw = (const unsigned*)&lv;
#pragma unroll
      for (int m = 0; m < 4; ++m) {
        const float x0 = us2f((unsigned short)(hw[m] & 0xFFFF)) +
                         us2f((unsigned short)(lw[m] & 0xFFFF));
        const float x1 = us2f((unsigned short)(hw[m] >> 16)) +
                         us2f((unsigned short)(lw[m] >> 16));
        acc = fmaf(x0, wcol[i + 2 * m], acc);
        acc = fmaf(x1, wcol[i + 2 * m + 1], acc);
      }
    }
    part[t] = acc;
    __syncthreads();
    if (t < 64) {
      const float y = part[t] + part[t + 64] + part[t + 128] + part[t + 192];
      atomicAdd(ybuf + (size_t)s * 4096 + g * 64 + t, y);
    }
    __syncthreads();
  }
}

__global__ void decide_fb(const float* __restrict__ ybuf,
                          const int* __restrict__ undec,
                          const int* __restrict__ count,
                          const float* __restrict__ bias,
                          const float* __restrict__ rand_u,
                          float* __restrict__ out) {
  __shared__ float gm[64];
  int n = *count;
  if (n > MAX_UNDEC) n = MAX_UNDEC;
  const int s = blockIdx.x;
  if (s >= n) return;
  const int t = threadIdx.x;
  const int g = t >> 2, p4 = t & 3;
  const float* yb = ybuf + (size_t)s * 4096;
  const int c0 = g * 64 + p4 * 16;
  float m = 3.4e38f;
#pragma unroll
  for (int e = 0; e < 16; ++e) m = fminf(m, yb[c0 + e] + bias[c0 + e]);
  m = fminf(m, __shfl_xor(m, 1, 64));
  m = fminf(m, __shfl_xor(m, 2, 64));
  if (p4 == 0) gm[g] = m;
  __syncthreads();
  if (t < 64) {
    float v = gm[t];
    v = fmaxf(v, __shfl_xor(v, 1, 64));
    v = fmaxf(v, __shfl_xor(v, 2, 64));
    v = fmaxf(v, __shfl_xor(v, 4, 64));
    v = fmaxf(v, __shfl_xor(v, 8, 64));
    v = fmaxf(v, __shfl_xor(v, 16, 64));
    v = fmaxf(v, __shfl_xor(v, 32, 64));
    if (t == 0) {
      const int row = undec[s];
      const float sg = 1.0f / (1.0f + expf(-v));
      out[row] = (rand_u[row] < sg) ? 1.0f : 0.0f;
    }
  }
}

extern "C" void kernel_launch(void* const* d_in, const int* in_sizes, int n_in,
                              void* d_out, int out_size, void* d_ws, size_t ws_size,
                              hipStream_t stream) {
  float* x = (float*)d_in[0];           // [8192, 2048] fp32
  float* weight = (float*)d_in[1];      // [4096, 2048] fp32
  const float* bias = (const float*)d_in[2];
  const float* rand_u = (const float*)d_in[3];
  const int* montn = (const int*)d_in[4];
  float* out = (float*)d_out;

  char* ws = (char*)d_ws;
  int* count = (int*)ws;                              // 4 B
  int* undec = (int*)(ws + 256);                      // 32 KB
  float* ybuf = (float*)(ws + 65536);                 // 1.5 MB (fallback)
  float* pmax = (float*)(ws + 65536 + 1572864);       // 512 KB [8192][16]
  unsigned* gmax = (unsigned*)(ws + 65536 + 1572864); // fallback alias (32 KB)

  // compact hi planes: xo 33.5 MB @ ws+4MB, wo 16.8 MB after.
  // ypart [16][96][4096] f32 = 25.2 MB ALIASES xo (dead after gemm).
  const size_t XO_OFF = (size_t)4 * 1024 * 1024;
  const size_t XO_BYTES = (size_t)8192 * 2048 * 2;
  const size_t WO_BYTES = (size_t)4096 * 2048 * 2;
  const bool big_ws = ws_size >= XO_OFF + XO_BYTES + WO_BYTES;

  if (big_ws) {
    unsigned short* xo = (unsigned short*)(ws + XO_OFF);
    unsigned short* wo = (unsigned short*)(ws + XO_OFF + XO_BYTES);
    float* ypart = (float*)(ws + XO_OFF);
    convert_hi<<<3072, 256, 0, stream>>>(x, weight, xo, wo, montn, count);
    gemm_minmax<<<1024, 256, 0, stream>>>(xo, wo, bias, pmax);
    finalize_margin<<<32, 256, 0, stream>>>(pmax, rand_u, out, count, undec);
    recompute_fp32<<<dim3(64, 16), 256, 0, stream>>>(x, weight, montn, count,
                                                     undec, ypart);
    decide<<<MAX_UNDEC, 256, 0, stream>>>(ypart, undec, count, bias, rand_u,
                                          out);
  } else {
    convert_split_fb<<<3104, 256, 0, stream>>>(x, weight, montn, count, gmax);
    gemm_minmax_fb<<<1024, 256, 0, stream>>>(
        (const unsigned short*)x, (const unsigned short*)weight, bias, gmax);
    finalize_margin_fb<<<384, 256, 0, stream>>>(gmax, rand_u, out, count,
                                                undec, (float4*)ybuf);
    recompute_rows_fb<<<dim3(64, 16), 256, 0, stream>>>(
        (const unsigned short*)x, (const unsigned short*)weight, count, undec,
        ybuf);
    decide_fb<<<MAX_UNDEC, 256, 0, stream>>>(ybuf, undec, count, bias, rand_u,
                                             out);
  }
}